// Round 13
// baseline (482.158 us; speedup 1.0000x reference)
//
#include <hip/hip_runtime.h>
#include <hip/hip_bf16.h>
#include <math.h>

#define DD 2048
#define SS 8192
#define VV 32002
#define RR 7
#define GATE 6144

typedef __attribute__((ext_vector_type(8))) short bfrag;   // 8 bf16 = 4 VGPRs
typedef __attribute__((ext_vector_type(4))) float f32x4;

// ---- static device scratch: referenced ONLY from device code ----
__device__ __attribute__((aligned(256))) float g_gia[GATE], g_gha[GATE], g_gib[GATE], g_ghb[GATE];
__device__ __attribute__((aligned(256))) float g_co[DD], g_cc[DD], g_ctx[DD], g_cb[DD];
__device__ __attribute__((aligned(256))) float g_alpha[SS];
__device__ __attribute__((aligned(256))) float g_spart[32 * SS];   // per (bn,wc) score partials

__device__ __forceinline__ float fsigmoid(float x) { return 1.0f / (1.0f + __expf(-x)); }
__device__ __forceinline__ float ftanh(float x)    { return 1.0f - 2.0f / (__expf(2.0f * x) + 1.0f); }

__global__ void diag_k(float* out, float v) { out[0] = v; }

// ---------------- init: zero ctx accumulator ----------------
__global__ void init_k() {
    int i = blockIdx.x * 256 + threadIdx.x;   // 2048 threads
    g_ctx[i] = 0.0f;
}

// ---------------- matvec: out[row] = W[row,:].x + bias[row]  (all f32) ----------------
// MODE 0: gi_a = W@partner   1: gh_a = W@cprev   2: gi_b = W@g_ctx   3: gh_b = W@g_co
template<int MODE>
__global__ __launch_bounds__(256) void matvec_k(const float* __restrict__ W,
                                                const float* __restrict__ x_in,
                                                const float* __restrict__ bias) {
    const float* x = (MODE == 2) ? g_ctx : (MODE == 3) ? g_co : x_in;
    float* out     = (MODE == 0) ? g_gia : (MODE == 1) ? g_gha : (MODE == 2) ? g_gib : g_ghb;
    int wv = threadIdx.x >> 6, lane = threadIdx.x & 63;
    int row = blockIdx.x * 4 + wv;
    if (row >= GATE) return;
    const float* wp = W + (size_t)row * DD;
    float acc = 0.0f;
#pragma unroll
    for (int j = 0; j < 4; ++j) {
        int base = j * 512 + lane * 8;
        f32x4 w0 = *(const f32x4*)&wp[base];
        f32x4 w1 = *(const f32x4*)&wp[base + 4];
        f32x4 x0 = *(const f32x4*)&x[base];
        f32x4 x1 = *(const f32x4*)&x[base + 4];
#pragma unroll
        for (int e = 0; e < 4; ++e) acc += w0[e] * x0[e] + w1[e] * x1[e];
    }
#pragma unroll
    for (int o = 1; o < 64; o <<= 1) acc += __shfl_xor(acc, o);
    if (lane == 0) out[row] = acc + bias[row];
}

// ---------------- GRU pointwise: c = (1-z)*n + z*h ----------------
// B=0: c_o from (g_gia, g_gha, h=cprev[arg]);  B=1: c_beta from (g_gib, g_ghb, h=g_co) + f32 out
template<int B>
__global__ void gru_out_k(const float* __restrict__ h_in, float* __restrict__ out_f) {
    const float* gi = B ? g_gib : g_gia;
    const float* gh = B ? g_ghb : g_gha;
    int d = blockIdx.x * 256 + threadIdx.x;   // 2048 threads
    float hh = B ? g_co[d] : h_in[d];
    float r = fsigmoid(gi[d] + gh[d]);
    float z = fsigmoid(gi[DD + d] + gh[DD + d]);
    float n = ftanh(gi[2 * DD + d] + r * gh[2 * DD + d]);
    float c = (1.0f - z) * n + z * hh;
    if (B) { g_cb[d] = c; out_f[d] = c; }
    else   { g_co[d] = c; }
}

// ---------------- cc[n] = W_co[n].c_o + W_cov[n].cov + b_enc+b_co+b_cov ----------------
__global__ __launch_bounds__(256) void cc_k(const float* __restrict__ Wco, const float* __restrict__ Wcov,
                                            const float* __restrict__ cov,
                                            const float* __restrict__ benc, const float* __restrict__ bco,
                                            const float* __restrict__ bcov) {
    int wv = threadIdx.x >> 6, lane = threadIdx.x & 63;
    int row = blockIdx.x * 4 + wv;   // 2048 rows
    const float* p1 = Wco + (size_t)row * DD;
    const float* p2 = Wcov + (size_t)row * DD;
    float acc = 0.0f;
#pragma unroll
    for (int j = 0; j < 4; ++j) {
        int base = j * 512 + lane * 8;
        f32x4 u0 = *(const f32x4*)&p1[base];
        f32x4 u1 = *(const f32x4*)&p1[base + 4];
        f32x4 v0 = *(const f32x4*)&p2[base];
        f32x4 v1 = *(const f32x4*)&p2[base + 4];
        f32x4 a0 = *(const f32x4*)&g_co[base];
        f32x4 a1 = *(const f32x4*)&g_co[base + 4];
        f32x4 b0 = *(const f32x4*)&cov[base];
        f32x4 b1 = *(const f32x4*)&cov[base + 4];
#pragma unroll
        for (int e = 0; e < 4; ++e)
            acc += u0[e] * a0[e] + u1[e] * a1[e] + v0[e] * b0[e] + v1[e] * b1[e];
    }
#pragma unroll
    for (int o = 1; o < 64; o <<= 1) acc += __shfl_xor(acc, o);
    if (lane == 0) g_cc[row] = acc + benc[row] + bco[row] + bcov[row];
}

// ---------------- f32 -> (bf16 hi, bf16 lo) split ----------------
__device__ __forceinline__ short f2bfbits(float v) {
    union { float f; unsigned int i; } c; c.f = v;
    unsigned int x = c.i;
    unsigned int r = (x + 0x7FFF + ((x >> 16) & 1)) >> 16;   // RNE
    return (short)r;
}
__device__ __forceinline__ float bfbits2f(short s) {
    union { unsigned int i; float f; } c; c.i = ((unsigned int)(unsigned short)s) << 16; return c.f;
}
__device__ __forceinline__ void split8(f32x4 v0, f32x4 v1, bfrag& hi, bfrag& lo) {
#pragma unroll
    for (int e = 0; e < 4; ++e) {
        float va = v0[e], vb = v1[e];
        short ha = f2bfbits(va), hb = f2bfbits(vb);
        short la = f2bfbits(va - bfbits2f(ha));
        short lb = f2bfbits(vb - bfbits2f(hb));
        hi[e] = ha; hi[4 + e] = hb;
        lo[e] = la; lo[4 + e] = lb;
    }
}

// ---------------- fused e-GEMM + tanh-score epilogue (f32 in, 3-pass bf16 MFMA) ----------------
// spart[(bn*2+wc)*SS + s] = sum over this wave's 64 n of tanh(e[s,n]+cc[n])*Wsc[n]
#define PAD 36
__global__ __launch_bounds__(256) void score_gemm_k(const float* __restrict__ A,   // enc [SS][DD]
                                                    const float* __restrict__ B,   // W_enc [DD][DD]
                                                    const float* __restrict__ Wsc) {
    __shared__ float As[128 * PAD];
    __shared__ float Bs[128 * PAD];
    const int tid = threadIdx.x;
    const int wave = tid >> 6, lane = tid & 63;
    const int bm = blockIdx.y, bn = blockIdx.x;   // grid (16, 64)
    const int wr = wave >> 1, wc = wave & 1;
    const int tr = tid >> 3;            // 0..31 staging row base
    const int tc = (tid & 7) * 4;       // 0..28 staging col
    const int rsel = lane & 15;
    const int kq = (lane >> 4) * 8;     // f32 col offset 0,8,16,24

    f32x4 acc[4][4];
#pragma unroll
    for (int m = 0; m < 4; ++m)
#pragma unroll
        for (int n = 0; n < 4; ++n) acc[m][n] = f32x4{0.f, 0.f, 0.f, 0.f};

    const float* gA0 = A + (size_t)(bm * 128) * DD;
    const float* gB0 = B + (size_t)(bn * 128) * DD;

    for (int k0 = 0; k0 < DD; k0 += 32) {
        f32x4 ra[4], rb[4];
#pragma unroll
        for (int j = 0; j < 4; ++j) {
            int row = tr + 32 * j;
            ra[j] = *(const f32x4*)&gA0[(size_t)row * DD + k0 + tc];
            rb[j] = *(const f32x4*)&gB0[(size_t)row * DD + k0 + tc];
        }
        __syncthreads();   // previous iteration's LDS reads complete
#pragma unroll
        for (int j = 0; j < 4; ++j) {
            int row = tr + 32 * j;
            *(f32x4*)&As[row * PAD + tc] = ra[j];
            *(f32x4*)&Bs[row * PAD + tc] = rb[j];
        }
        __syncthreads();   // writes visible

        bfrag ah[4], al[4], bh[4], bl[4];
#pragma unroll
        for (int m = 0; m < 4; ++m) {
            int base = (wr * 64 + m * 16 + rsel) * PAD + kq;
            split8(*(const f32x4*)&As[base], *(const f32x4*)&As[base + 4], ah[m], al[m]);
        }
#pragma unroll
        for (int n = 0; n < 4; ++n) {
            int base = (wc * 64 + n * 16 + rsel) * PAD + kq;
            split8(*(const f32x4*)&Bs[base], *(const f32x4*)&Bs[base + 4], bh[n], bl[n]);
        }
#pragma unroll
        for (int m = 0; m < 4; ++m)
#pragma unroll
            for (int n = 0; n < 4; ++n) {
                acc[m][n] = __builtin_amdgcn_mfma_f32_16x16x32_bf16(ah[m], bh[n], acc[m][n], 0, 0, 0);
                acc[m][n] = __builtin_amdgcn_mfma_f32_16x16x32_bf16(al[m], bh[n], acc[m][n], 0, 0, 0);
                acc[m][n] = __builtin_amdgcn_mfma_f32_16x16x32_bf16(ah[m], bl[n], acc[m][n], 0, 0, 0);
            }
    }

    // epilogue: tanh + weighted reduce over this wave's 64 n-columns
    const int cl = lane & 15, gq = lane >> 4;
    float ccv[4], wv[4];
#pragma unroll
    for (int nf = 0; nf < 4; ++nf) {
        int n = bn * 128 + wc * 64 + nf * 16 + cl;
        ccv[nf] = g_cc[n];
        wv[nf] = Wsc[n];
    }
    float* sp = &g_spart[(size_t)(bn * 2 + wc) * SS + bm * 128 + wr * 64];
#pragma unroll
    for (int m = 0; m < 4; ++m) {
#pragma unroll
        for (int r = 0; r < 4; ++r) {
            float v = 0.0f;
#pragma unroll
            for (int nf = 0; nf < 4; ++nf) v += ftanh(acc[m][nf][r] + ccv[nf]) * wv[nf];
            v += __shfl_xor(v, 1); v += __shfl_xor(v, 2);
            v += __shfl_xor(v, 4); v += __shfl_xor(v, 8);
            if (cl == 0) sp[m * 16 + gq * 4 + r] = v;
        }
    }
}

// ---------------- softmax over 32 partial slabs (b_score dropped: shift-invariant) ----------------
__global__ __launch_bounds__(1024) void softmax_k(float* __restrict__ out_alpha) {
    __shared__ float red[16];
    __shared__ float sval;
    int t = threadIdx.x, lane = t & 63, w = t >> 6;
    float loc[8];
    float m = -1e30f;
#pragma unroll
    for (int i = 0; i < 8; ++i) {
        int idx = t + i * 1024;
        float s = 0.0f;
        for (int p = 0; p < 32; ++p) s += g_spart[(size_t)p * SS + idx];
        loc[i] = s;
        m = fmaxf(m, s);
    }
#pragma unroll
    for (int o = 1; o < 64; o <<= 1) m = fmaxf(m, __shfl_xor(m, o));
    if (lane == 0) red[w] = m;
    __syncthreads();
    if (t == 0) { float mm = red[0]; for (int i = 1; i < 16; ++i) mm = fmaxf(mm, red[i]); sval = mm; }
    __syncthreads();
    float mx = sval, s = 0.0f;
#pragma unroll
    for (int i = 0; i < 8; ++i) { loc[i] = __expf(loc[i] - mx); s += loc[i]; }
#pragma unroll
    for (int o = 1; o < 64; o <<= 1) s += __shfl_xor(s, o);
    if (lane == 0) red[w] = s;
    __syncthreads();
    if (t == 0) { float ss = 0; for (int i = 0; i < 16; ++i) ss += red[i]; sval = ss; }
    __syncthreads();
    float inv = 1.0f / sval;
#pragma unroll
    for (int i = 0; i < 8; ++i) {
        float a = loc[i] * inv;
        g_alpha[t + i * 1024] = a;
        out_alpha[t + i * 1024] = a;
    }
}

// ---------------- ctx += alpha @ enc ----------------
__global__ __launch_bounds__(256) void ctx_partial_k(const float* __restrict__ enc) {
    int t = threadIdx.x, b = blockIdx.x;   // 128 blocks x 64 s-rows
    int d0 = t * 8;
    float acc[8] = {0, 0, 0, 0, 0, 0, 0, 0};
    int s0 = b * 64;
    for (int s = s0; s < s0 + 64; ++s) {
        f32x4 v0 = *(const f32x4*)&enc[(size_t)s * DD + d0];
        f32x4 v1 = *(const f32x4*)&enc[(size_t)s * DD + d0 + 4];
        float a = g_alpha[s];
#pragma unroll
        for (int e = 0; e < 4; ++e) { acc[e] += a * v0[e]; acc[4 + e] += a * v1[e]; }
    }
#pragma unroll
    for (int e = 0; e < 8; ++e) atomicAdd(&g_ctx[d0 + e], acc[e]);
}

// ---------------- heads: rows 0..VV-1 = W_sym, VV..VV+RR-1 = W_rel (f32 out) ----------------
__global__ __launch_bounds__(256) void heads_k(const float* __restrict__ Wsym, const float* __restrict__ bsym,
                                               const float* __restrict__ Wrel, const float* __restrict__ brel,
                                               float* __restrict__ out) {
    int wv = threadIdx.x >> 6, lane = threadIdx.x & 63;
    int row = blockIdx.x * 4 + wv;
    if (row >= VV + RR) return;
    const float* wp;
    float bb;
    if (row < VV) { wp = Wsym + (size_t)row * DD; bb = bsym[row]; }
    else          { wp = Wrel + (size_t)(row - VV) * DD; bb = brel[row - VV]; }
    float acc = 0.0f;
#pragma unroll
    for (int j = 0; j < 4; ++j) {
        int base = j * 512 + lane * 8;
        f32x4 w0 = *(const f32x4*)&wp[base];
        f32x4 w1 = *(const f32x4*)&wp[base + 4];
        f32x4 x0 = *(const f32x4*)&g_cb[base];
        f32x4 x1 = *(const f32x4*)&g_cb[base + 4];
#pragma unroll
        for (int e = 0; e < 4; ++e) acc += w0[e] * x0[e] + w1[e] * x1[e];
    }
#pragma unroll
    for (int o = 1; o < 64; o <<= 1) acc += __shfl_xor(acc, o);
    if (lane == 0) out[row] = acc + bb;
}

extern "C" void kernel_launch(void* const* d_in, const int* in_sizes, int n_in,
                              void* d_out, int out_size, void* d_ws, size_t ws_size,
                              hipStream_t stream) {
    float* out = (float*)d_out;   // OUTPUT IS FLOAT32 (round-12 oracle)

    static const int expected[24] = {
        SS * DD, DD, DD, DD,
        3 * DD * DD, 3 * DD * DD, 3 * DD, 3 * DD,
        3 * DD * DD, 3 * DD * DD, 3 * DD, 3 * DD,
        DD * DD, DD, DD * DD, DD, DD * DD, DD,
        DD, 1, VV * DD, VV, RR * DD, RR
    };
    if (n_in != 24) { diag_k<<<1, 1, 0, stream>>>(out, 4.0e7f); return; }
    for (int i = 0; i < 24; ++i)
        if (in_sizes[i] != expected[i]) { diag_k<<<1, 1, 0, stream>>>(out, 3.0e7f + (i + 1) * 1.0e5f); return; }

    const float* enc     = (const float*)d_in[0];
    const float* cprev   = (const float*)d_in[1];
    const float* partner = (const float*)d_in[2];
    const float* cov     = (const float*)d_in[3];
    const float* Wih_a   = (const float*)d_in[4];
    const float* Whh_a   = (const float*)d_in[5];
    const float* bih_a   = (const float*)d_in[6];
    const float* bhh_a   = (const float*)d_in[7];
    const float* Wih_b   = (const float*)d_in[8];
    const float* Whh_b   = (const float*)d_in[9];
    const float* bih_b   = (const float*)d_in[10];
    const float* bhh_b   = (const float*)d_in[11];
    const float* W_enc   = (const float*)d_in[12];
    const float* b_enc   = (const float*)d_in[13];
    const float* W_co    = (const float*)d_in[14];
    const float* b_co    = (const float*)d_in[15];
    const float* W_cov   = (const float*)d_in[16];
    const float* b_cov   = (const float*)d_in[17];
    const float* W_score = (const float*)d_in[18];
    const float* W_sym   = (const float*)d_in[20];
    const float* b_sym   = (const float*)d_in[21];
    const float* W_rel   = (const float*)d_in[22];
    const float* b_rel   = (const float*)d_in[23];

    init_k<<<8, 256, 0, stream>>>();
    matvec_k<0><<<GATE / 4, 256, 0, stream>>>(Wih_a, partner, bih_a);
    matvec_k<1><<<GATE / 4, 256, 0, stream>>>(Whh_a, cprev, bhh_a);
    gru_out_k<0><<<8, 256, 0, stream>>>(cprev, nullptr);
    cc_k<<<DD / 4, 256, 0, stream>>>(W_co, W_cov, cov, b_enc, b_co, b_cov);
    score_gemm_k<<<dim3(16, 64), 256, 0, stream>>>(enc, W_enc, W_score);
    softmax_k<<<1, 1024, 0, stream>>>(out + VV + RR + DD);
    ctx_partial_k<<<128, 256, 0, stream>>>(enc);
    matvec_k<2><<<GATE / 4, 256, 0, stream>>>(Wih_b, cprev, bih_b);
    matvec_k<3><<<GATE / 4, 256, 0, stream>>>(Whh_b, cprev, bhh_b);
    gru_out_k<1><<<8, 256, 0, stream>>>(cprev, out + VV + RR);
    heads_k<<<(VV + RR + 3) / 4, 256, 0, stream>>>(W_sym, b_sym, W_rel, b_rel, out);
}

// Round 14
// 287.289 us; speedup vs baseline: 1.6783x; 1.6783x over previous
//
#include <hip/hip_runtime.h>
#include <hip/hip_bf16.h>
#include <math.h>

#define DD 2048
#define SS 8192
#define VV 32002
#define RR 7
#define GATE 6144
#define PADS 40   // u16 per LDS row: 80B stride -> 16B aligned, ~2-way banks (free)

typedef unsigned short u16;
typedef __attribute__((ext_vector_type(8))) unsigned short u16x8;
typedef __attribute__((ext_vector_type(8))) short bfrag;   // 8 bf16 = 4 VGPRs
typedef __attribute__((ext_vector_type(4))) float f32x4;

// ---- static device scratch: referenced ONLY from device code ----
__device__ __attribute__((aligned(256))) u16 g_ah[(size_t)SS * DD];   // enc as bf16 (32 MB)
__device__ __attribute__((aligned(256))) u16 g_bh[(size_t)DD * DD];   // W_enc as bf16 (8 MB)
__device__ __attribute__((aligned(256))) float g_gia[GATE], g_gha[GATE], g_gib[GATE], g_ghb[GATE];
__device__ __attribute__((aligned(256))) float g_co[DD], g_cc[DD], g_ctx[DD], g_cb[DD];
__device__ __attribute__((aligned(256))) float g_alpha[SS];
__device__ __attribute__((aligned(256))) float g_spart[32 * SS];

__device__ __forceinline__ float fsigmoid(float x) { return 1.0f / (1.0f + __expf(-x)); }
__device__ __forceinline__ float ftanh(float x)    { return 1.0f - 2.0f / (__expf(2.0f * x) + 1.0f); }
__device__ __forceinline__ u16 f2bf(float v) {
    union { float f; unsigned int i; } c; c.f = v;
    return (u16)((c.i + 0x7FFF + ((c.i >> 16) & 1)) >> 16);   // RNE
}

__global__ void diag_k(float* out, float v) { out[0] = v; }

// ---------------- presplit: f32 -> bf16(hi) once (WHICH 0: enc, 1: W_enc) ----------------
template<int WHICH>
__global__ __launch_bounds__(256) void presplit_k(const float* __restrict__ src) {
    u16* dst = WHICH ? g_bh : g_ah;
    size_t i = ((size_t)blockIdx.x * 256 + threadIdx.x) * 8;
    f32x4 v0 = *(const f32x4*)&src[i];
    f32x4 v1 = *(const f32x4*)&src[i + 4];
    u16x8 h;
#pragma unroll
    for (int e = 0; e < 4; ++e) { h[e] = f2bf(v0[e]); h[4 + e] = f2bf(v1[e]); }
    *(u16x8*)&dst[i] = h;
}

// ---------------- init: zero ctx accumulator ----------------
__global__ void init_k() {
    int i = blockIdx.x * 256 + threadIdx.x;   // 2048 threads
    g_ctx[i] = 0.0f;
}

// ---------------- matvec: out[row] = W[row,:].x + bias[row]  (all f32) ----------------
template<int MODE>
__global__ __launch_bounds__(256) void matvec_k(const float* __restrict__ W,
                                                const float* __restrict__ x_in,
                                                const float* __restrict__ bias) {
    const float* x = (MODE == 2) ? g_ctx : (MODE == 3) ? g_co : x_in;
    float* out     = (MODE == 0) ? g_gia : (MODE == 1) ? g_gha : (MODE == 2) ? g_gib : g_ghb;
    int wv = threadIdx.x >> 6, lane = threadIdx.x & 63;
    int row = blockIdx.x * 4 + wv;
    if (row >= GATE) return;
    const float* wp = W + (size_t)row * DD;
    float acc = 0.0f;
#pragma unroll
    for (int j = 0; j < 4; ++j) {
        int base = j * 512 + lane * 8;
        f32x4 w0 = *(const f32x4*)&wp[base];
        f32x4 w1 = *(const f32x4*)&wp[base + 4];
        f32x4 x0 = *(const f32x4*)&x[base];
        f32x4 x1 = *(const f32x4*)&x[base + 4];
#pragma unroll
        for (int e = 0; e < 4; ++e) acc += w0[e] * x0[e] + w1[e] * x1[e];
    }
#pragma unroll
    for (int o = 1; o < 64; o <<= 1) acc += __shfl_xor(acc, o);
    if (lane == 0) out[row] = acc + bias[row];
}

// ---------------- GRU pointwise ----------------
template<int B>
__global__ void gru_out_k(const float* __restrict__ h_in, float* __restrict__ out_f) {
    const float* gi = B ? g_gib : g_gia;
    const float* gh = B ? g_ghb : g_gha;
    int d = blockIdx.x * 256 + threadIdx.x;
    float hh = B ? g_co[d] : h_in[d];
    float r = fsigmoid(gi[d] + gh[d]);
    float z = fsigmoid(gi[DD + d] + gh[DD + d]);
    float n = ftanh(gi[2 * DD + d] + r * gh[2 * DD + d]);
    float c = (1.0f - z) * n + z * hh;
    if (B) { g_cb[d] = c; out_f[d] = c; }
    else   { g_co[d] = c; }
}

// ---------------- cc[n] = W_co[n].c_o + W_cov[n].cov + b_enc+b_co+b_cov ----------------
__global__ __launch_bounds__(256) void cc_k(const float* __restrict__ Wco, const float* __restrict__ Wcov,
                                            const float* __restrict__ cov,
                                            const float* __restrict__ benc, const float* __restrict__ bco,
                                            const float* __restrict__ bcov) {
    int wv = threadIdx.x >> 6, lane = threadIdx.x & 63;
    int row = blockIdx.x * 4 + wv;
    const float* p1 = Wco + (size_t)row * DD;
    const float* p2 = Wcov + (size_t)row * DD;
    float acc = 0.0f;
#pragma unroll
    for (int j = 0; j < 4; ++j) {
        int base = j * 512 + lane * 8;
        f32x4 u0 = *(const f32x4*)&p1[base];
        f32x4 u1 = *(const f32x4*)&p1[base + 4];
        f32x4 v0 = *(const f32x4*)&p2[base];
        f32x4 v1 = *(const f32x4*)&p2[base + 4];
        f32x4 a0 = *(const f32x4*)&g_co[base];
        f32x4 a1 = *(const f32x4*)&g_co[base + 4];
        f32x4 b0 = *(const f32x4*)&cov[base];
        f32x4 b1 = *(const f32x4*)&cov[base + 4];
#pragma unroll
        for (int e = 0; e < 4; ++e)
            acc += u0[e] * a0[e] + u1[e] * a1[e] + v0[e] * b0[e] + v1[e] * b1[e];
    }
#pragma unroll
    for (int o = 1; o < 64; o <<= 1) acc += __shfl_xor(acc, o);
    if (lane == 0) g_cc[row] = acc + benc[row] + bco[row] + bcov[row];
}

// ---------------- fused e-GEMM + tanh-score epilogue (pure bf16 MFMA, 1 pass) ----------------
__global__ __launch_bounds__(256) void score_gemm_k(const float* __restrict__ Wsc) {
    __shared__ u16 As[128 * PADS];
    __shared__ u16 Bs[128 * PADS];
    const int tid = threadIdx.x;
    const int wave = tid >> 6, lane = tid & 63;
    const int bm = blockIdx.y, bn = blockIdx.x;   // grid (16, 64)
    const int wr = wave >> 1, wc = wave & 1;
    const int rsel = lane & 15;
    const int kq = (lane >> 4) * 8;

    // staging units: 128 rows x 4 col-groups (8 shorts = 16B); thread -> units tid, tid+256
    const int r0 = tid >> 2, c0 = (tid & 3) * 8;
    const int r1 = (tid + 256) >> 2, c1 = c0;

    f32x4 acc[4][4];
#pragma unroll
    for (int m = 0; m < 4; ++m)
#pragma unroll
        for (int n = 0; n < 4; ++n) acc[m][n] = f32x4{0.f, 0.f, 0.f, 0.f};

    const u16* gA = g_ah + (size_t)(bm * 128) * DD;
    const u16* gB = g_bh + (size_t)(bn * 128) * DD;

    for (int k0 = 0; k0 < DD; k0 += 32) {
        u16x8 a0 = *(const u16x8*)&gA[(size_t)r0 * DD + k0 + c0];
        u16x8 a1 = *(const u16x8*)&gA[(size_t)r1 * DD + k0 + c1];
        u16x8 b0 = *(const u16x8*)&gB[(size_t)r0 * DD + k0 + c0];
        u16x8 b1 = *(const u16x8*)&gB[(size_t)r1 * DD + k0 + c1];
        __syncthreads();   // previous iteration's LDS reads complete
        *(u16x8*)&As[r0 * PADS + c0] = a0;
        *(u16x8*)&As[r1 * PADS + c1] = a1;
        *(u16x8*)&Bs[r0 * PADS + c0] = b0;
        *(u16x8*)&Bs[r1 * PADS + c1] = b1;
        __syncthreads();   // writes visible
        bfrag a[4], b[4];
#pragma unroll
        for (int m = 0; m < 4; ++m) a[m] = *(const bfrag*)&As[(wr * 64 + m * 16 + rsel) * PADS + kq];
#pragma unroll
        for (int n = 0; n < 4; ++n) b[n] = *(const bfrag*)&Bs[(wc * 64 + n * 16 + rsel) * PADS + kq];
#pragma unroll
        for (int m = 0; m < 4; ++m)
#pragma unroll
            for (int n = 0; n < 4; ++n)
                acc[m][n] = __builtin_amdgcn_mfma_f32_16x16x32_bf16(a[m], b[n], acc[m][n], 0, 0, 0);
    }

    // epilogue: tanh + weighted reduce over this wave's 64 n-columns
    const int cl = lane & 15, gq = lane >> 4;
    float ccv[4], wv[4];
#pragma unroll
    for (int nf = 0; nf < 4; ++nf) {
        int n = bn * 128 + wc * 64 + nf * 16 + cl;
        ccv[nf] = g_cc[n];
        wv[nf] = Wsc[n];
    }
    float* sp = &g_spart[(size_t)(bn * 2 + wc) * SS + bm * 128 + wr * 64];
#pragma unroll
    for (int m = 0; m < 4; ++m) {
#pragma unroll
        for (int r = 0; r < 4; ++r) {
            float v = 0.0f;
#pragma unroll
            for (int nf = 0; nf < 4; ++nf) v += ftanh(acc[m][nf][r] + ccv[nf]) * wv[nf];
            v += __shfl_xor(v, 1); v += __shfl_xor(v, 2);
            v += __shfl_xor(v, 4); v += __shfl_xor(v, 8);
            if (cl == 0) sp[m * 16 + gq * 4 + r] = v;
        }
    }
}

// ---------------- softmax over 32 partial slabs ----------------
__global__ __launch_bounds__(1024) void softmax_k(float* __restrict__ out_alpha) {
    __shared__ float red[16];
    __shared__ float sval;
    int t = threadIdx.x, lane = t & 63, w = t >> 6;
    float loc[8];
    float m = -1e30f;
#pragma unroll
    for (int i = 0; i < 8; ++i) {
        int idx = t + i * 1024;
        float s = 0.0f;
        for (int p = 0; p < 32; ++p) s += g_spart[(size_t)p * SS + idx];
        loc[i] = s;
        m = fmaxf(m, s);
    }
#pragma unroll
    for (int o = 1; o < 64; o <<= 1) m = fmaxf(m, __shfl_xor(m, o));
    if (lane == 0) red[w] = m;
    __syncthreads();
    if (t == 0) { float mm = red[0]; for (int i = 1; i < 16; ++i) mm = fmaxf(mm, red[i]); sval = mm; }
    __syncthreads();
    float mx = sval, s = 0.0f;
#pragma unroll
    for (int i = 0; i < 8; ++i) { loc[i] = __expf(loc[i] - mx); s += loc[i]; }
#pragma unroll
    for (int o = 1; o < 64; o <<= 1) s += __shfl_xor(s, o);
    if (lane == 0) red[w] = s;
    __syncthreads();
    if (t == 0) { float ss = 0; for (int i = 0; i < 16; ++i) ss += red[i]; sval = ss; }
    __syncthreads();
    float inv = 1.0f / sval;
#pragma unroll
    for (int i = 0; i < 8; ++i) {
        float a = loc[i] * inv;
        g_alpha[t + i * 1024] = a;
        out_alpha[t + i * 1024] = a;
    }
}

// ---------------- ctx += alpha @ enc ----------------
__global__ __launch_bounds__(256) void ctx_partial_k(const float* __restrict__ enc) {
    int t = threadIdx.x, b = blockIdx.x;   // 128 blocks x 64 s-rows
    int d0 = t * 8;
    float acc[8] = {0, 0, 0, 0, 0, 0, 0, 0};
    int s0 = b * 64;
    for (int s = s0; s < s0 + 64; ++s) {
        f32x4 v0 = *(const f32x4*)&enc[(size_t)s * DD + d0];
        f32x4 v1 = *(const f32x4*)&enc[(size_t)s * DD + d0 + 4];
        float a = g_alpha[s];
#pragma unroll
        for (int e = 0; e < 4; ++e) { acc[e] += a * v0[e]; acc[4 + e] += a * v1[e]; }
    }
#pragma unroll
    for (int e = 0; e < 8; ++e) atomicAdd(&g_ctx[d0 + e], acc[e]);
}

// ---------------- heads ----------------
__global__ __launch_bounds__(256) void heads_k(const float* __restrict__ Wsym, const float* __restrict__ bsym,
                                               const float* __restrict__ Wrel, const float* __restrict__ brel,
                                               float* __restrict__ out) {
    int wv = threadIdx.x >> 6, lane = threadIdx.x & 63;
    int row = blockIdx.x * 4 + wv;
    if (row >= VV + RR) return;
    const float* wp;
    float bb;
    if (row < VV) { wp = Wsym + (size_t)row * DD; bb = bsym[row]; }
    else          { wp = Wrel + (size_t)(row - VV) * DD; bb = brel[row - VV]; }
    float acc = 0.0f;
#pragma unroll
    for (int j = 0; j < 4; ++j) {
        int base = j * 512 + lane * 8;
        f32x4 w0 = *(const f32x4*)&wp[base];
        f32x4 w1 = *(const f32x4*)&wp[base + 4];
        f32x4 x0 = *(const f32x4*)&g_cb[base];
        f32x4 x1 = *(const f32x4*)&g_cb[base + 4];
#pragma unroll
        for (int e = 0; e < 4; ++e) acc += w0[e] * x0[e] + w1[e] * x1[e];
    }
#pragma unroll
    for (int o = 1; o < 64; o <<= 1) acc += __shfl_xor(acc, o);
    if (lane == 0) out[row] = acc + bb;
}

extern "C" void kernel_launch(void* const* d_in, const int* in_sizes, int n_in,
                              void* d_out, int out_size, void* d_ws, size_t ws_size,
                              hipStream_t stream) {
    float* out = (float*)d_out;   // f32 outputs (round-12 oracle)

    static const int expected[24] = {
        SS * DD, DD, DD, DD,
        3 * DD * DD, 3 * DD * DD, 3 * DD, 3 * DD,
        3 * DD * DD, 3 * DD * DD, 3 * DD, 3 * DD,
        DD * DD, DD, DD * DD, DD, DD * DD, DD,
        DD, 1, VV * DD, VV, RR * DD, RR
    };
    if (n_in != 24) { diag_k<<<1, 1, 0, stream>>>(out, 4.0e7f); return; }
    for (int i = 0; i < 24; ++i)
        if (in_sizes[i] != expected[i]) { diag_k<<<1, 1, 0, stream>>>(out, 3.0e7f + (i + 1) * 1.0e5f); return; }

    const float* enc     = (const float*)d_in[0];
    const float* cprev   = (const float*)d_in[1];
    const float* partner = (const float*)d_in[2];
    const float* cov     = (const float*)d_in[3];
    const float* Wih_a   = (const float*)d_in[4];
    const float* Whh_a   = (const float*)d_in[5];
    const float* bih_a   = (const float*)d_in[6];
    const float* bhh_a   = (const float*)d_in[7];
    const float* Wih_b   = (const float*)d_in[8];
    const float* Whh_b   = (const float*)d_in[9];
    const float* bih_b   = (const float*)d_in[10];
    const float* bhh_b   = (const float*)d_in[11];
    const float* W_enc   = (const float*)d_in[12];
    const float* b_enc   = (const float*)d_in[13];
    const float* W_co    = (const float*)d_in[14];
    const float* b_co    = (const float*)d_in[15];
    const float* W_cov   = (const float*)d_in[16];
    const float* b_cov   = (const float*)d_in[17];
    const float* W_score = (const float*)d_in[18];
    const float* W_sym   = (const float*)d_in[20];
    const float* b_sym   = (const float*)d_in[21];
    const float* W_rel   = (const float*)d_in[22];
    const float* b_rel   = (const float*)d_in[23];

    init_k<<<8, 256, 0, stream>>>();
    presplit_k<0><<<SS * DD / (256 * 8), 256, 0, stream>>>(enc);     // 8192 blocks
    presplit_k<1><<<DD * DD / (256 * 8), 256, 0, stream>>>(W_enc);   // 2048 blocks
    matvec_k<0><<<GATE / 4, 256, 0, stream>>>(Wih_a, partner, bih_a);
    matvec_k<1><<<GATE / 4, 256, 0, stream>>>(Whh_a, cprev, bhh_a);
    gru_out_k<0><<<8, 256, 0, stream>>>(cprev, nullptr);
    cc_k<<<DD / 4, 256, 0, stream>>>(W_co, W_cov, cov, b_enc, b_co, b_cov);
    score_gemm_k<<<dim3(16, 64), 256, 0, stream>>>(W_score);
    softmax_k<<<1, 1024, 0, stream>>>(out + VV + RR + DD);
    ctx_partial_k<<<128, 256, 0, stream>>>(enc);
    matvec_k<2><<<GATE / 4, 256, 0, stream>>>(Wih_b, cprev, bih_b);
    matvec_k<3><<<GATE / 4, 256, 0, stream>>>(Whh_b, cprev, bhh_b);
    gru_out_k<1><<<8, 256, 0, stream>>>(cprev, out + VV + RR);
    heads_k<<<(VV + RR + 3) / 4, 256, 0, stream>>>(W_sym, b_sym, W_rel, b_rel, out);
}

// Round 15
// 281.097 us; speedup vs baseline: 1.7153x; 1.0220x over previous
//
#include <hip/hip_runtime.h>
#include <hip/hip_bf16.h>
#include <math.h>

#define DD 2048
#define SS 8192
#define VV 32002
#define RR 7
#define GATE 6144

typedef unsigned short u16;
typedef __attribute__((ext_vector_type(8))) unsigned short u16x8;
typedef __attribute__((ext_vector_type(8))) short bfrag;   // 8 bf16 = 4 VGPRs
typedef __attribute__((ext_vector_type(4))) float f32x4;

// ---- static device scratch: referenced ONLY from device code ----
__device__ __attribute__((aligned(256))) u16 g_ah[(size_t)SS * DD];   // enc as bf16 (32 MB)
__device__ __attribute__((aligned(256))) u16 g_bh[(size_t)DD * DD];   // W_enc as bf16 (8 MB)
__device__ __attribute__((aligned(256))) float g_gia[GATE], g_gha[GATE], g_gib[GATE], g_ghb[GATE];
__device__ __attribute__((aligned(256))) float g_co[DD], g_cc[DD], g_ctx[DD], g_cb[DD];
__device__ __attribute__((aligned(256))) float g_alpha[SS];
__device__ __attribute__((aligned(256))) float g_spart[32 * SS];

__device__ __forceinline__ float fsigmoid(float x) { return 1.0f / (1.0f + __expf(-x)); }
__device__ __forceinline__ float ftanh(float x)    { return 1.0f - 2.0f / (__expf(2.0f * x) + 1.0f); }
__device__ __forceinline__ u16 f2bf(float v) {
    union { float f; unsigned int i; } c; c.f = v;
    return (u16)((c.i + 0x7FFF + ((c.i >> 16) & 1)) >> 16);   // RNE
}
__device__ __forceinline__ float bf2f(u16 u) {
    union { unsigned int i; float f; } c; c.i = ((unsigned int)u) << 16; return c.f;
}
__device__ __forceinline__ void gload16(const void* g, void* l) {
    __builtin_amdgcn_global_load_lds(
        (const __attribute__((address_space(1))) void*)g,
        (__attribute__((address_space(3))) void*)l, 16, 0, 0);
}

__global__ void diag_k(float* out, float v) { out[0] = v; }

// ---------------- presplit: f32 -> bf16 once (WHICH 0: enc, 1: W_enc) ----------------
template<int WHICH>
__global__ __launch_bounds__(256) void presplit_k(const float* __restrict__ src) {
    u16* dst = WHICH ? g_bh : g_ah;
    size_t i = ((size_t)blockIdx.x * 256 + threadIdx.x) * 8;
    f32x4 v0 = *(const f32x4*)&src[i];
    f32x4 v1 = *(const f32x4*)&src[i + 4];
    u16x8 h;
#pragma unroll
    for (int e = 0; e < 4; ++e) { h[e] = f2bf(v0[e]); h[4 + e] = f2bf(v1[e]); }
    *(u16x8*)&dst[i] = h;
}

// ---------------- init: zero ctx accumulator ----------------
__global__ void init_k() {
    int i = blockIdx.x * 256 + threadIdx.x;   // 2048 threads
    g_ctx[i] = 0.0f;
}

// ---------------- matvec: out[row] = W[row,:].x + bias[row]  (all f32) ----------------
template<int MODE>
__global__ __launch_bounds__(256) void matvec_k(const float* __restrict__ W,
                                                const float* __restrict__ x_in,
                                                const float* __restrict__ bias) {
    const float* x = (MODE == 2) ? g_ctx : (MODE == 3) ? g_co : x_in;
    float* out     = (MODE == 0) ? g_gia : (MODE == 1) ? g_gha : (MODE == 2) ? g_gib : g_ghb;
    int wv = threadIdx.x >> 6, lane = threadIdx.x & 63;
    int row = blockIdx.x * 4 + wv;
    if (row >= GATE) return;
    const float* wp = W + (size_t)row * DD;
    float acc = 0.0f;
#pragma unroll
    for (int j = 0; j < 4; ++j) {
        int base = j * 512 + lane * 8;
        f32x4 w0 = *(const f32x4*)&wp[base];
        f32x4 w1 = *(const f32x4*)&wp[base + 4];
        f32x4 x0 = *(const f32x4*)&x[base];
        f32x4 x1 = *(const f32x4*)&x[base + 4];
#pragma unroll
        for (int e = 0; e < 4; ++e) acc += w0[e] * x0[e] + w1[e] * x1[e];
    }
#pragma unroll
    for (int o = 1; o < 64; o <<= 1) acc += __shfl_xor(acc, o);
    if (lane == 0) out[row] = acc + bias[row];
}

// ---------------- GRU pointwise ----------------
template<int B>
__global__ void gru_out_k(const float* __restrict__ h_in, float* __restrict__ out_f) {
    const float* gi = B ? g_gib : g_gia;
    const float* gh = B ? g_ghb : g_gha;
    int d = blockIdx.x * 256 + threadIdx.x;
    float hh = B ? g_co[d] : h_in[d];
    float r = fsigmoid(gi[d] + gh[d]);
    float z = fsigmoid(gi[DD + d] + gh[DD + d]);
    float n = ftanh(gi[2 * DD + d] + r * gh[2 * DD + d]);
    float c = (1.0f - z) * n + z * hh;
    if (B) { g_cb[d] = c; out_f[d] = c; }
    else   { g_co[d] = c; }
}

// ---------------- cc[n] = W_co[n].c_o + W_cov[n].cov + b_enc+b_co+b_cov ----------------
__global__ __launch_bounds__(256) void cc_k(const float* __restrict__ Wco, const float* __restrict__ Wcov,
                                            const float* __restrict__ cov,
                                            const float* __restrict__ benc, const float* __restrict__ bco,
                                            const float* __restrict__ bcov) {
    int wv = threadIdx.x >> 6, lane = threadIdx.x & 63;
    int row = blockIdx.x * 4 + wv;
    const float* p1 = Wco + (size_t)row * DD;
    const float* p2 = Wcov + (size_t)row * DD;
    float acc = 0.0f;
#pragma unroll
    for (int j = 0; j < 4; ++j) {
        int base = j * 512 + lane * 8;
        f32x4 u0 = *(const f32x4*)&p1[base];
        f32x4 u1 = *(const f32x4*)&p1[base + 4];
        f32x4 v0 = *(const f32x4*)&p2[base];
        f32x4 v1 = *(const f32x4*)&p2[base + 4];
        f32x4 a0 = *(const f32x4*)&g_co[base];
        f32x4 a1 = *(const f32x4*)&g_co[base + 4];
        f32x4 b0 = *(const f32x4*)&cov[base];
        f32x4 b1 = *(const f32x4*)&cov[base + 4];
#pragma unroll
        for (int e = 0; e < 4; ++e)
            acc += u0[e] * a0[e] + u1[e] * a1[e] + v0[e] * b0[e] + v1[e] * b1[e];
    }
#pragma unroll
    for (int o = 1; o < 64; o <<= 1) acc += __shfl_xor(acc, o);
    if (lane == 0) g_cc[row] = acc + benc[row] + bco[row] + bcov[row];
}

// ---------------- fused e-GEMM + tanh-score epilogue (m97 structure) ----------------
// linear LDS [128][32] u16, global_load_lds width 16, 2 barriers/K-step
__global__ __launch_bounds__(256) void score_gemm_k(const float* __restrict__ Wsc) {
    __shared__ u16 As[128 * 32];
    __shared__ u16 Bs[128 * 32];
    const int tid = threadIdx.x;
    const int wave = tid >> 6, lane = tid & 63;
    const int bm = blockIdx.y, bn = blockIdx.x;   // grid (16, 64)
    const int wr = wave >> 1, wc = wave & 1;
    const int srow = lane >> 2, scol = (lane & 3) * 8;
    const int rsel = lane & 15;
    const int kq = (lane >> 4) * 8;
    const int c0 = wave * 2, c1 = wave * 2 + 1;

    f32x4 acc[4][4];
#pragma unroll
    for (int m = 0; m < 4; ++m)
#pragma unroll
        for (int n = 0; n < 4; ++n) acc[m][n] = f32x4{0.f, 0.f, 0.f, 0.f};

    const u16* gA = g_ah + (size_t)(bm * 128) * DD;
    const u16* gB = g_bh + (size_t)(bn * 128) * DD;

    for (int k0 = 0; k0 < DD; k0 += 32) {
        gload16(gA + (size_t)(c0 * 16 + srow) * DD + k0 + scol, &As[c0 * 512]);
        gload16(gA + (size_t)(c1 * 16 + srow) * DD + k0 + scol, &As[c1 * 512]);
        gload16(gB + (size_t)(c0 * 16 + srow) * DD + k0 + scol, &Bs[c0 * 512]);
        gload16(gB + (size_t)(c1 * 16 + srow) * DD + k0 + scol, &Bs[c1 * 512]);
        __syncthreads();   // drains vmcnt -> staged tile visible
        bfrag a[4], b[4];
#pragma unroll
        for (int m = 0; m < 4; ++m) a[m] = *(const bfrag*)&As[(wr * 64 + m * 16 + rsel) * 32 + kq];
#pragma unroll
        for (int n = 0; n < 4; ++n) b[n] = *(const bfrag*)&Bs[(wc * 64 + n * 16 + rsel) * 32 + kq];
#pragma unroll
        for (int m = 0; m < 4; ++m)
#pragma unroll
            for (int n = 0; n < 4; ++n)
                acc[m][n] = __builtin_amdgcn_mfma_f32_16x16x32_bf16(a[m], b[n], acc[m][n], 0, 0, 0);
        __syncthreads();   // frag reads complete before next stage overwrites
    }

    // epilogue: tanh + weighted reduce over this wave's 64 n-columns
    const int cl = lane & 15, gq = lane >> 4;
    float ccv[4], wv[4];
#pragma unroll
    for (int nf = 0; nf < 4; ++nf) {
        int n = bn * 128 + wc * 64 + nf * 16 + cl;
        ccv[nf] = g_cc[n];
        wv[nf] = Wsc[n];
    }
    float* sp = &g_spart[(size_t)(bn * 2 + wc) * SS + bm * 128 + wr * 64];
#pragma unroll
    for (int m = 0; m < 4; ++m) {
#pragma unroll
        for (int r = 0; r < 4; ++r) {
            float v = 0.0f;
#pragma unroll
            for (int nf = 0; nf < 4; ++nf) v += ftanh(acc[m][nf][r] + ccv[nf]) * wv[nf];
            v += __shfl_xor(v, 1); v += __shfl_xor(v, 2);
            v += __shfl_xor(v, 4); v += __shfl_xor(v, 8);
            if (cl == 0) sp[m * 16 + gq * 4 + r] = v;
        }
    }
}

// ---------------- softmax over 32 partial slabs ----------------
__global__ __launch_bounds__(1024) void softmax_k(float* __restrict__ out_alpha) {
    __shared__ float red[16];
    __shared__ float sval;
    int t = threadIdx.x, lane = t & 63, w = t >> 6;
    float loc[8];
    float m = -1e30f;
#pragma unroll
    for (int i = 0; i < 8; ++i) {
        int idx = t + i * 1024;
        float s = 0.0f;
        for (int p = 0; p < 32; ++p) s += g_spart[(size_t)p * SS + idx];
        loc[i] = s;
        m = fmaxf(m, s);
    }
#pragma unroll
    for (int o = 1; o < 64; o <<= 1) m = fmaxf(m, __shfl_xor(m, o));
    if (lane == 0) red[w] = m;
    __syncthreads();
    if (t == 0) { float mm = red[0]; for (int i = 1; i < 16; ++i) mm = fmaxf(mm, red[i]); sval = mm; }
    __syncthreads();
    float mx = sval, s = 0.0f;
#pragma unroll
    for (int i = 0; i < 8; ++i) { loc[i] = __expf(loc[i] - mx); s += loc[i]; }
#pragma unroll
    for (int o = 1; o < 64; o <<= 1) s += __shfl_xor(s, o);
    if (lane == 0) red[w] = s;
    __syncthreads();
    if (t == 0) { float ss = 0; for (int i = 0; i < 16; ++i) ss += red[i]; sval = ss; }
    __syncthreads();
    float inv = 1.0f / sval;
#pragma unroll
    for (int i = 0; i < 8; ++i) {
        float a = loc[i] * inv;
        g_alpha[t + i * 1024] = a;
        out_alpha[t + i * 1024] = a;
    }
}

// ---------------- ctx += alpha @ enc  (bf16 enc from g_ah: half the bytes) ----------------
__global__ __launch_bounds__(256) void ctx_partial_k() {
    int t = threadIdx.x, b = blockIdx.x;   // 128 blocks x 64 s-rows
    int d0 = t * 8;
    float acc[8] = {0, 0, 0, 0, 0, 0, 0, 0};
    int s0 = b * 64;
    for (int s = s0; s < s0 + 64; ++s) {
        u16x8 v = *(const u16x8*)&g_ah[(size_t)s * DD + d0];
        float a = g_alpha[s];
#pragma unroll
        for (int e = 0; e < 8; ++e) acc[e] += a * bf2f(v[e]);
    }
#pragma unroll
    for (int e = 0; e < 8; ++e) atomicAdd(&g_ctx[d0 + e], acc[e]);
}

// ---------------- heads ----------------
__global__ __launch_bounds__(256) void heads_k(const float* __restrict__ Wsym, const float* __restrict__ bsym,
                                               const float* __restrict__ Wrel, const float* __restrict__ brel,
                                               float* __restrict__ out) {
    int wv = threadIdx.x >> 6, lane = threadIdx.x & 63;
    int row = blockIdx.x * 4 + wv;
    if (row >= VV + RR) return;
    const float* wp;
    float bb;
    if (row < VV) { wp = Wsym + (size_t)row * DD; bb = bsym[row]; }
    else          { wp = Wrel + (size_t)(row - VV) * DD; bb = brel[row - VV]; }
    float acc = 0.0f;
#pragma unroll
    for (int j = 0; j < 4; ++j) {
        int base = j * 512 + lane * 8;
        f32x4 w0 = *(const f32x4*)&wp[base];
        f32x4 w1 = *(const f32x4*)&wp[base + 4];
        f32x4 x0 = *(const f32x4*)&g_cb[base];
        f32x4 x1 = *(const f32x4*)&g_cb[base + 4];
#pragma unroll
        for (int e = 0; e < 4; ++e) acc += w0[e] * x0[e] + w1[e] * x1[e];
    }
#pragma unroll
    for (int o = 1; o < 64; o <<= 1) acc += __shfl_xor(acc, o);
    if (lane == 0) out[row] = acc + bb;
}

extern "C" void kernel_launch(void* const* d_in, const int* in_sizes, int n_in,
                              void* d_out, int out_size, void* d_ws, size_t ws_size,
                              hipStream_t stream) {
    float* out = (float*)d_out;   // f32 outputs

    static const int expected[24] = {
        SS * DD, DD, DD, DD,
        3 * DD * DD, 3 * DD * DD, 3 * DD, 3 * DD,
        3 * DD * DD, 3 * DD * DD, 3 * DD, 3 * DD,
        DD * DD, DD, DD * DD, DD, DD * DD, DD,
        DD, 1, VV * DD, VV, RR * DD, RR
    };
    if (n_in != 24) { diag_k<<<1, 1, 0, stream>>>(out, 4.0e7f); return; }
    for (int i = 0; i < 24; ++i)
        if (in_sizes[i] != expected[i]) { diag_k<<<1, 1, 0, stream>>>(out, 3.0e7f + (i + 1) * 1.0e5f); return; }

    const float* enc     = (const float*)d_in[0];
    const float* cprev   = (const float*)d_in[1];
    const float* partner = (const float*)d_in[2];
    const float* cov     = (const float*)d_in[3];
    const float* Wih_a   = (const float*)d_in[4];
    const float* Whh_a   = (const float*)d_in[5];
    const float* bih_a   = (const float*)d_in[6];
    const float* bhh_a   = (const float*)d_in[7];
    const float* Wih_b   = (const float*)d_in[8];
    const float* Whh_b   = (const float*)d_in[9];
    const float* bih_b   = (const float*)d_in[10];
    const float* bhh_b   = (const float*)d_in[11];
    const float* W_enc   = (const float*)d_in[12];
    const float* b_enc   = (const float*)d_in[13];
    const float* W_co    = (const float*)d_in[14];
    const float* b_co    = (const float*)d_in[15];
    const float* W_cov   = (const float*)d_in[16];
    const float* b_cov   = (const float*)d_in[17];
    const float* W_score = (const float*)d_in[18];
    const float* W_sym   = (const float*)d_in[20];
    const float* b_sym   = (const float*)d_in[21];
    const float* W_rel   = (const float*)d_in[22];
    const float* b_rel   = (const float*)d_in[23];

    init_k<<<8, 256, 0, stream>>>();
    presplit_k<0><<<SS * DD / (256 * 8), 256, 0, stream>>>(enc);
    presplit_k<1><<<DD * DD / (256 * 8), 256, 0, stream>>>(W_enc);
    matvec_k<0><<<GATE / 4, 256, 0, stream>>>(Wih_a, partner, bih_a);
    matvec_k<1><<<GATE / 4, 256, 0, stream>>>(Whh_a, cprev, bhh_a);
    gru_out_k<0><<<8, 256, 0, stream>>>(cprev, nullptr);
    cc_k<<<DD / 4, 256, 0, stream>>>(W_co, W_cov, cov, b_enc, b_co, b_cov);
    score_gemm_k<<<dim3(16, 64), 256, 0, stream>>>(W_score);
    softmax_k<<<1, 1024, 0, stream>>>(out + VV + RR + DD);
    ctx_partial_k<<<128, 256, 0, stream>>>();
    matvec_k<2><<<GATE / 4, 256, 0, stream>>>(Wih_b, cprev, bih_b);
    matvec_k<3><<<GATE / 4, 256, 0, stream>>>(Whh_b, cprev, bhh_b);
    gru_out_k<1><<<8, 256, 0, stream>>>(cprev, out + VV + RR);
    heads_k<<<(VV + RR + 3) / 4, 256, 0, stream>>>(W_sym, b_sym, W_rel, b_rel, out);
}

// Round 16
// 268.545 us; speedup vs baseline: 1.7954x; 1.0467x over previous
//
#include <hip/hip_runtime.h>
#include <hip/hip_bf16.h>
#include <math.h>

#define DD 2048
#define SS 8192
#define VV 32002
#define RR 7
#define GATE 6144

typedef unsigned short u16;
typedef __attribute__((ext_vector_type(8))) unsigned short u16x8;
typedef __attribute__((ext_vector_type(8))) short bfrag;   // 8 bf16 = 4 VGPRs
typedef __attribute__((ext_vector_type(4))) float f32x4;

// ---- static device scratch: referenced ONLY from device code ----
__device__ __attribute__((aligned(256))) u16 g_ah[(size_t)SS * DD];   // enc as bf16 (32 MB)
__device__ __attribute__((aligned(256))) u16 g_bh[(size_t)DD * DD];   // W_enc as bf16 (8 MB)
__device__ __attribute__((aligned(256))) float g_gia[GATE], g_gha[GATE], g_gib[GATE], g_ghb[GATE];
__device__ __attribute__((aligned(256))) float g_co[DD], g_cc[DD], g_ctx[DD], g_cb[DD];
__device__ __attribute__((aligned(256))) float g_alpha[SS];
__device__ __attribute__((aligned(256))) float g_scores[SS];

__device__ __forceinline__ float fsigmoid(float x) { return 1.0f / (1.0f + __expf(-x)); }
__device__ __forceinline__ float ftanh(float x)    { return 1.0f - 2.0f / (__expf(2.0f * x) + 1.0f); }
__device__ __forceinline__ u16 f2bf(float v) {
    union { float f; unsigned int i; } c; c.f = v;
    return (u16)((c.i + 0x7FFF + ((c.i >> 16) & 1)) >> 16);   // RNE
}
__device__ __forceinline__ float bf2f(u16 u) {
    union { unsigned int i; float f; } c; c.i = ((unsigned int)u) << 16; return c.f;
}
__device__ __forceinline__ void gload16(const void* g, void* l) {
    __builtin_amdgcn_global_load_lds(
        (const __attribute__((address_space(1))) void*)g,
        (__attribute__((address_space(3))) void*)l, 16, 0, 0);
}

__global__ void diag_k(float* out, float v) { out[0] = v; }

// ---------------- presplit: f32 -> bf16 once (WHICH 0: enc, 1: W_enc) ----------------
template<int WHICH>
__global__ __launch_bounds__(256) void presplit_k(const float* __restrict__ src) {
    u16* dst = WHICH ? g_bh : g_ah;
    size_t i = ((size_t)blockIdx.x * 256 + threadIdx.x) * 8;
    f32x4 v0 = *(const f32x4*)&src[i];
    f32x4 v1 = *(const f32x4*)&src[i + 4];
    u16x8 h;
#pragma unroll
    for (int e = 0; e < 4; ++e) { h[e] = f2bf(v0[e]); h[4 + e] = f2bf(v1[e]); }
    *(u16x8*)&dst[i] = h;
}

// ---------------- init: zero scores + ctx accumulators ----------------
__global__ void init_k() {
    int i = blockIdx.x * 256 + threadIdx.x;   // 8192 threads
    g_scores[i] = 0.0f;
    if (i < DD) g_ctx[i] = 0.0f;
}

// ---------------- matvec: out[row] = W[row,:].x + bias[row]  (all f32) ----------------
template<int MODE>
__global__ __launch_bounds__(256) void matvec_k(const float* __restrict__ W,
                                                const float* __restrict__ x_in,
                                                const float* __restrict__ bias) {
    const float* x = (MODE == 2) ? g_ctx : (MODE == 3) ? g_co : x_in;
    float* out     = (MODE == 0) ? g_gia : (MODE == 1) ? g_gha : (MODE == 2) ? g_gib : g_ghb;
    int wv = threadIdx.x >> 6, lane = threadIdx.x & 63;
    int row = blockIdx.x * 4 + wv;
    if (row >= GATE) return;
    const float* wp = W + (size_t)row * DD;
    float acc = 0.0f;
#pragma unroll
    for (int j = 0; j < 4; ++j) {
        int base = j * 512 + lane * 8;
        f32x4 w0 = *(const f32x4*)&wp[base];
        f32x4 w1 = *(const f32x4*)&wp[base + 4];
        f32x4 x0 = *(const f32x4*)&x[base];
        f32x4 x1 = *(const f32x4*)&x[base + 4];
#pragma unroll
        for (int e = 0; e < 4; ++e) acc += w0[e] * x0[e] + w1[e] * x1[e];
    }
#pragma unroll
    for (int o = 1; o < 64; o <<= 1) acc += __shfl_xor(acc, o);
    if (lane == 0) out[row] = acc + bias[row];
}

// ---------------- GRU pointwise ----------------
template<int B>
__global__ void gru_out_k(const float* __restrict__ h_in, float* __restrict__ out_f) {
    const float* gi = B ? g_gib : g_gia;
    const float* gh = B ? g_ghb : g_gha;
    int d = blockIdx.x * 256 + threadIdx.x;
    float hh = B ? g_co[d] : h_in[d];
    float r = fsigmoid(gi[d] + gh[d]);
    float z = fsigmoid(gi[DD + d] + gh[DD + d]);
    float n = ftanh(gi[2 * DD + d] + r * gh[2 * DD + d]);
    float c = (1.0f - z) * n + z * hh;
    if (B) { g_cb[d] = c; out_f[d] = c; }
    else   { g_co[d] = c; }
}

// ---------------- cc[n] = W_co[n].c_o + W_cov[n].cov + b_enc+b_co+b_cov ----------------
__global__ __launch_bounds__(256) void cc_k(const float* __restrict__ Wco, const float* __restrict__ Wcov,
                                            const float* __restrict__ cov,
                                            const float* __restrict__ benc, const float* __restrict__ bco,
                                            const float* __restrict__ bcov) {
    int wv = threadIdx.x >> 6, lane = threadIdx.x & 63;
    int row = blockIdx.x * 4 + wv;
    const float* p1 = Wco + (size_t)row * DD;
    const float* p2 = Wcov + (size_t)row * DD;
    float acc = 0.0f;
#pragma unroll
    for (int j = 0; j < 4; ++j) {
        int base = j * 512 + lane * 8;
        f32x4 u0 = *(const f32x4*)&p1[base];
        f32x4 u1 = *(const f32x4*)&p1[base + 4];
        f32x4 v0 = *(const f32x4*)&p2[base];
        f32x4 v1 = *(const f32x4*)&p2[base + 4];
        f32x4 a0 = *(const f32x4*)&g_co[base];
        f32x4 a1 = *(const f32x4*)&g_co[base + 4];
        f32x4 b0 = *(const f32x4*)&cov[base];
        f32x4 b1 = *(const f32x4*)&cov[base + 4];
#pragma unroll
        for (int e = 0; e < 4; ++e)
            acc += u0[e] * a0[e] + u1[e] * a1[e] + v0[e] * b0[e] + v1[e] * b1[e];
    }
#pragma unroll
    for (int o = 1; o < 64; o <<= 1) acc += __shfl_xor(acc, o);
    if (lane == 0) g_cc[row] = acc + benc[row] + bco[row] + bcov[row];
}

// ---------------- fused e-GEMM + tanh-score epilogue (m97 + XCD swizzle) ----------------
// 1D grid 1024; swz=(bid&7)*128+(bid>>3): each XCD gets 8 consecutive bm x all 16 bn
// -> per-XCD A working set 4MB (L2-fit), B streamed once per XCD.
__global__ __launch_bounds__(256) void score_gemm_k(const float* __restrict__ Wsc) {
    __shared__ u16 As[128 * 32];
    __shared__ u16 Bs[128 * 32];
    const int bid = blockIdx.x;
    const int swz = (bid & 7) * 128 + (bid >> 3);
    const int bm = swz >> 4;      // 0..63
    const int bn = swz & 15;      // 0..15
    const int tid = threadIdx.x;
    const int wave = tid >> 6, lane = tid & 63;
    const int wr = wave >> 1, wc = wave & 1;
    const int srow = lane >> 2, scol = (lane & 3) * 8;
    const int rsel = lane & 15;
    const int kq = (lane >> 4) * 8;
    const int c0 = wave * 2, c1 = wave * 2 + 1;

    f32x4 acc[4][4];
#pragma unroll
    for (int m = 0; m < 4; ++m)
#pragma unroll
        for (int n = 0; n < 4; ++n) acc[m][n] = f32x4{0.f, 0.f, 0.f, 0.f};

    const u16* gA = g_ah + (size_t)(bm * 128) * DD;
    const u16* gB = g_bh + (size_t)(bn * 128) * DD;

    for (int k0 = 0; k0 < DD; k0 += 32) {
        gload16(gA + (size_t)(c0 * 16 + srow) * DD + k0 + scol, &As[c0 * 512]);
        gload16(gA + (size_t)(c1 * 16 + srow) * DD + k0 + scol, &As[c1 * 512]);
        gload16(gB + (size_t)(c0 * 16 + srow) * DD + k0 + scol, &Bs[c0 * 512]);
        gload16(gB + (size_t)(c1 * 16 + srow) * DD + k0 + scol, &Bs[c1 * 512]);
        __syncthreads();
        bfrag a[4], b[4];
#pragma unroll
        for (int m = 0; m < 4; ++m) a[m] = *(const bfrag*)&As[(wr * 64 + m * 16 + rsel) * 32 + kq];
#pragma unroll
        for (int n = 0; n < 4; ++n) b[n] = *(const bfrag*)&Bs[(wc * 64 + n * 16 + rsel) * 32 + kq];
#pragma unroll
        for (int m = 0; m < 4; ++m)
#pragma unroll
            for (int n = 0; n < 4; ++n)
                acc[m][n] = __builtin_amdgcn_mfma_f32_16x16x32_bf16(a[m], b[n], acc[m][n], 0, 0, 0);
        __syncthreads();
    }

    // epilogue: tanh + weighted reduce over this wave's 64 n-columns -> atomic scores
    const int cl = lane & 15, gq = lane >> 4;
    float ccv[4], wv[4];
#pragma unroll
    for (int nf = 0; nf < 4; ++nf) {
        int n = bn * 128 + wc * 64 + nf * 16 + cl;
        ccv[nf] = g_cc[n];
        wv[nf] = Wsc[n];
    }
#pragma unroll
    for (int m = 0; m < 4; ++m) {
#pragma unroll
        for (int r = 0; r < 4; ++r) {
            float v = 0.0f;
#pragma unroll
            for (int nf = 0; nf < 4; ++nf) v += ftanh(acc[m][nf][r] + ccv[nf]) * wv[nf];
            v += __shfl_xor(v, 1); v += __shfl_xor(v, 2);
            v += __shfl_xor(v, 4); v += __shfl_xor(v, 8);
            if (cl == 0) atomicAdd(&g_scores[bm * 128 + wr * 64 + m * 16 + gq * 4 + r], v);
        }
    }
}

// ---------------- softmax over 8192 scores ----------------
__global__ __launch_bounds__(1024) void softmax_k(float* __restrict__ out_alpha) {
    __shared__ float red[16];
    __shared__ float sval;
    int t = threadIdx.x, lane = t & 63, w = t >> 6;
    float loc[8];
    float m = -1e30f;
#pragma unroll
    for (int i = 0; i < 8; ++i) {
        loc[i] = g_scores[t + i * 1024];
        m = fmaxf(m, loc[i]);
    }
#pragma unroll
    for (int o = 1; o < 64; o <<= 1) m = fmaxf(m, __shfl_xor(m, o));
    if (lane == 0) red[w] = m;
    __syncthreads();
    if (t == 0) { float mm = red[0]; for (int i = 1; i < 16; ++i) mm = fmaxf(mm, red[i]); sval = mm; }
    __syncthreads();
    float mx = sval, s = 0.0f;
#pragma unroll
    for (int i = 0; i < 8; ++i) { loc[i] = __expf(loc[i] - mx); s += loc[i]; }
#pragma unroll
    for (int o = 1; o < 64; o <<= 1) s += __shfl_xor(s, o);
    if (lane == 0) red[w] = s;
    __syncthreads();
    if (t == 0) { float ss = 0; for (int i = 0; i < 16; ++i) ss += red[i]; sval = ss; }
    __syncthreads();
    float inv = 1.0f / sval;
#pragma unroll
    for (int i = 0; i < 8; ++i) {
        float a = loc[i] * inv;
        g_alpha[t + i * 1024] = a;
        out_alpha[t + i * 1024] = a;
    }
}

// ---------------- ctx += alpha @ enc  (bf16 enc from g_ah) ----------------
__global__ __launch_bounds__(256) void ctx_partial_k() {
    int t = threadIdx.x, b = blockIdx.x;   // 128 blocks x 64 s-rows
    int d0 = t * 8;
    float acc[8] = {0, 0, 0, 0, 0, 0, 0, 0};
    int s0 = b * 64;
    for (int s = s0; s < s0 + 64; ++s) {
        u16x8 v = *(const u16x8*)&g_ah[(size_t)s * DD + d0];
        float a = g_alpha[s];
#pragma unroll
        for (int e = 0; e < 8; ++e) acc[e] += a * bf2f(v[e]);
    }
#pragma unroll
    for (int e = 0; e < 8; ++e) atomicAdd(&g_ctx[d0 + e], acc[e]);
}

// ---------------- heads ----------------
__global__ __launch_bounds__(256) void heads_k(const float* __restrict__ Wsym, const float* __restrict__ bsym,
                                               const float* __restrict__ Wrel, const float* __restrict__ brel,
                                               float* __restrict__ out) {
    int wv = threadIdx.x >> 6, lane = threadIdx.x & 63;
    int row = blockIdx.x * 4 + wv;
    if (row >= VV + RR) return;
    const float* wp;
    float bb;
    if (row < VV) { wp = Wsym + (size_t)row * DD; bb = bsym[row]; }
    else          { wp = Wrel + (size_t)(row - VV) * DD; bb = brel[row - VV]; }
    float acc = 0.0f;
#pragma unroll
    for (int j = 0; j < 4; ++j) {
        int base = j * 512 + lane * 8;
        f32x4 w0 = *(const f32x4*)&wp[base];
        f32x4 w1 = *(const f32x4*)&wp[base + 4];
        f32x4 x0 = *(const f32x4*)&g_cb[base];
        f32x4 x1 = *(const f32x4*)&g_cb[base + 4];
#pragma unroll
        for (int e = 0; e < 4; ++e) acc += w0[e] * x0[e] + w1[e] * x1[e];
    }
#pragma unroll
    for (int o = 1; o < 64; o <<= 1) acc += __shfl_xor(acc, o);
    if (lane == 0) out[row] = acc + bb;
}

extern "C" void kernel_launch(void* const* d_in, const int* in_sizes, int n_in,
                              void* d_out, int out_size, void* d_ws, size_t ws_size,
                              hipStream_t stream) {
    float* out = (float*)d_out;   // f32 outputs

    static const int expected[24] = {
        SS * DD, DD, DD, DD,
        3 * DD * DD, 3 * DD * DD, 3 * DD, 3 * DD,
        3 * DD * DD, 3 * DD * DD, 3 * DD, 3 * DD,
        DD * DD, DD, DD * DD, DD, DD * DD, DD,
        DD, 1, VV * DD, VV, RR * DD, RR
    };
    if (n_in != 24) { diag_k<<<1, 1, 0, stream>>>(out, 4.0e7f); return; }
    for (int i = 0; i < 24; ++i)
        if (in_sizes[i] != expected[i]) { diag_k<<<1, 1, 0, stream>>>(out, 3.0e7f + (i + 1) * 1.0e5f); return; }

    const float* enc     = (const float*)d_in[0];
    const float* cprev   = (const float*)d_in[1];
    const float* partner = (const float*)d_in[2];
    const float* cov     = (const float*)d_in[3];
    const float* Wih_a   = (const float*)d_in[4];
    const float* Whh_a   = (const float*)d_in[5];
    const float* bih_a   = (const float*)d_in[6];
    const float* bhh_a   = (const float*)d_in[7];
    const float* Wih_b   = (const float*)d_in[8];
    const float* Whh_b   = (const float*)d_in[9];
    const float* bih_b   = (const float*)d_in[10];
    const float* bhh_b   = (const float*)d_in[11];
    const float* W_enc   = (const float*)d_in[12];
    const float* b_enc   = (const float*)d_in[13];
    const float* W_co    = (const float*)d_in[14];
    const float* b_co    = (const float*)d_in[15];
    const float* W_cov   = (const float*)d_in[16];
    const float* b_cov   = (const float*)d_in[17];
    const float* W_score = (const float*)d_in[18];
    const float* W_sym   = (const float*)d_in[20];
    const float* b_sym   = (const float*)d_in[21];
    const float* W_rel   = (const float*)d_in[22];
    const float* b_rel   = (const float*)d_in[23];

    init_k<<<32, 256, 0, stream>>>();
    presplit_k<0><<<SS * DD / (256 * 8), 256, 0, stream>>>(enc);
    presplit_k<1><<<DD * DD / (256 * 8), 256, 0, stream>>>(W_enc);
    matvec_k<0><<<GATE / 4, 256, 0, stream>>>(Wih_a, partner, bih_a);
    matvec_k<1><<<GATE / 4, 256, 0, stream>>>(Whh_a, cprev, bhh_a);
    gru_out_k<0><<<8, 256, 0, stream>>>(cprev, nullptr);
    cc_k<<<DD / 4, 256, 0, stream>>>(W_co, W_cov, cov, b_enc, b_co, b_cov);
    score_gemm_k<<<1024, 256, 0, stream>>>(W_score);
    softmax_k<<<1, 1024, 0, stream>>>(out + VV + RR + DD);
    ctx_partial_k<<<128, 256, 0, stream>>>();
    matvec_k<2><<<GATE / 4, 256, 0, stream>>>(Wih_b, cprev, bih_b);
    matvec_k<3><<<GATE / 4, 256, 0, stream>>>(Whh_b, cprev, bhh_b);
    gru_out_k<1><<<8, 256, 0, stream>>>(cprev, out + VV + RR);
    heads_k<<<(VV + RR + 3) / 4, 256, 0, stream>>>(W_sym, b_sym, W_rel, b_rel, out);
}

// Round 17
// 268.529 us; speedup vs baseline: 1.7956x; 1.0001x over previous
//
#include <hip/hip_runtime.h>
#include <hip/hip_bf16.h>
#include <math.h>

#define DD 2048
#define SS 8192
#define VV 32002
#define RR 7
#define GATE 6144

typedef unsigned short u16;
typedef __attribute__((ext_vector_type(8))) unsigned short u16x8;
typedef __attribute__((ext_vector_type(8))) short bfrag;   // 8 bf16 = 4 VGPRs
typedef __attribute__((ext_vector_type(4))) float f32x4;

// ---- static device scratch: referenced ONLY from device code ----
__device__ __attribute__((aligned(256))) u16 g_ah[(size_t)SS * DD];   // enc as bf16 (32 MB)
__device__ __attribute__((aligned(256))) u16 g_bh[(size_t)DD * DD];   // W_enc as bf16 (8 MB)
__device__ __attribute__((aligned(256))) float g_gia[GATE], g_gha[GATE], g_gib[GATE], g_ghb[GATE];
__device__ __attribute__((aligned(256))) float g_co[DD], g_cc[DD], g_ctx[DD], g_cb[DD];
__device__ __attribute__((aligned(256))) float g_alpha[SS];
__device__ __attribute__((aligned(256))) float g_scores[SS];

__device__ __forceinline__ float fsigmoid(float x) { return 1.0f / (1.0f + __expf(-x)); }
__device__ __forceinline__ float ftanh(float x)    { return 1.0f - 2.0f / (__expf(2.0f * x) + 1.0f); }
__device__ __forceinline__ u16 f2bf(float v) {
    union { float f; unsigned int i; } c; c.f = v;
    return (u16)((c.i + 0x7FFF + ((c.i >> 16) & 1)) >> 16);   // RNE
}
__device__ __forceinline__ float bf2f(u16 u) {
    union { unsigned int i; float f; } c; c.i = ((unsigned int)u) << 16; return c.f;
}
__device__ __forceinline__ void gload16(const void* g, void* l) {
    __builtin_amdgcn_global_load_lds(
        (const __attribute__((address_space(1))) void*)g,
        (__attribute__((address_space(3))) void*)l, 16, 0, 0);
}

__global__ void diag_k(float* out, float v) { out[0] = v; }

// ---------------- presplit: f32 -> bf16 once (WHICH 0: enc, 1: W_enc + zero-init) ----------------
template<int WHICH>
__global__ __launch_bounds__(256) void presplit_k(const float* __restrict__ src) {
    u16* dst = WHICH ? g_bh : g_ah;
    size_t i = ((size_t)blockIdx.x * 256 + threadIdx.x) * 8;
    f32x4 v0 = *(const f32x4*)&src[i];
    f32x4 v1 = *(const f32x4*)&src[i + 4];
    u16x8 h;
#pragma unroll
    for (int e = 0; e < 4; ++e) { h[e] = f2bf(v0[e]); h[4 + e] = f2bf(v1[e]); }
    *(u16x8*)&dst[i] = h;
    if (WHICH == 1) {   // fold zero-init of accumulators into this launch
        int gt = blockIdx.x * 256 + threadIdx.x;
        if (gt < SS) g_scores[gt] = 0.0f;
        if (gt < DD) g_ctx[gt] = 0.0f;
    }
}

// ---------------- fused matvec pair: PAIR 0 -> {gi_a, gh_a}, PAIR 1 -> {gi_b, gh_b} ----------------
template<int PAIR>
__global__ __launch_bounds__(256) void matvec2_k(const float* __restrict__ W0,
                                                 const float* __restrict__ W1,
                                                 const float* __restrict__ x0_in,
                                                 const float* __restrict__ x1_in,
                                                 const float* __restrict__ b0,
                                                 const float* __restrict__ b1) {
    const int half = blockIdx.x >= (GATE / 4);
    const float* W    = half ? W1 : W0;
    const float* bias = half ? b1 : b0;
    const float* x;
    float* out;
    if (PAIR == 0) { x = half ? x1_in : x0_in; out = half ? g_gha : g_gia; }
    else           { x = half ? g_co  : g_ctx; out = half ? g_ghb : g_gib; }
    int wv = threadIdx.x >> 6, lane = threadIdx.x & 63;
    int row = (blockIdx.x - half * (GATE / 4)) * 4 + wv;
    const float* wp = W + (size_t)row * DD;
    float acc = 0.0f;
#pragma unroll
    for (int j = 0; j < 4; ++j) {
        int base = j * 512 + lane * 8;
        f32x4 w0 = *(const f32x4*)&wp[base];
        f32x4 w1 = *(const f32x4*)&wp[base + 4];
        f32x4 x0 = *(const f32x4*)&x[base];
        f32x4 x1 = *(const f32x4*)&x[base + 4];
#pragma unroll
        for (int e = 0; e < 4; ++e) acc += w0[e] * x0[e] + w1[e] * x1[e];
    }
#pragma unroll
    for (int o = 1; o < 64; o <<= 1) acc += __shfl_xor(acc, o);
    if (lane == 0) out[row] = acc + bias[row];
}

// ---------------- GRU pointwise ----------------
template<int B>
__global__ void gru_out_k(const float* __restrict__ h_in, float* __restrict__ out_f) {
    const float* gi = B ? g_gib : g_gia;
    const float* gh = B ? g_ghb : g_gha;
    int d = blockIdx.x * 256 + threadIdx.x;
    float hh = B ? g_co[d] : h_in[d];
    float r = fsigmoid(gi[d] + gh[d]);
    float z = fsigmoid(gi[DD + d] + gh[DD + d]);
    float n = ftanh(gi[2 * DD + d] + r * gh[2 * DD + d]);
    float c = (1.0f - z) * n + z * hh;
    if (B) { g_cb[d] = c; out_f[d] = c; }
    else   { g_co[d] = c; }
}

// ---------------- cc[n] = W_co[n].c_o + W_cov[n].cov + b_enc+b_co+b_cov ----------------
__global__ __launch_bounds__(256) void cc_k(const float* __restrict__ Wco, const float* __restrict__ Wcov,
                                            const float* __restrict__ cov,
                                            const float* __restrict__ benc, const float* __restrict__ bco,
                                            const float* __restrict__ bcov) {
    int wv = threadIdx.x >> 6, lane = threadIdx.x & 63;
    int row = blockIdx.x * 4 + wv;
    const float* p1 = Wco + (size_t)row * DD;
    const float* p2 = Wcov + (size_t)row * DD;
    float acc = 0.0f;
#pragma unroll
    for (int j = 0; j < 4; ++j) {
        int base = j * 512 + lane * 8;
        f32x4 u0 = *(const f32x4*)&p1[base];
        f32x4 u1 = *(const f32x4*)&p1[base + 4];
        f32x4 v0 = *(const f32x4*)&p2[base];
        f32x4 v1 = *(const f32x4*)&p2[base + 4];
        f32x4 a0 = *(const f32x4*)&g_co[base];
        f32x4 a1 = *(const f32x4*)&g_co[base + 4];
        f32x4 b0 = *(const f32x4*)&cov[base];
        f32x4 b1 = *(const f32x4*)&cov[base + 4];
#pragma unroll
        for (int e = 0; e < 4; ++e)
            acc += u0[e] * a0[e] + u1[e] * a1[e] + v0[e] * b0[e] + v1[e] * b1[e];
    }
#pragma unroll
    for (int o = 1; o < 64; o <<= 1) acc += __shfl_xor(acc, o);
    if (lane == 0) g_cc[row] = acc + benc[row] + bco[row] + bcov[row];
}

// ---------------- fused e-GEMM + tanh-score epilogue ----------------
// T3 2-phase: dbuf LDS, prefetch t+1 issued BEFORE compute of t, ONE barrier/step.
__global__ __launch_bounds__(256) void score_gemm_k(const float* __restrict__ Wsc) {
    __shared__ u16 As[2][128 * 32];
    __shared__ u16 Bs[2][128 * 32];
    const int bid = blockIdx.x;
    const int swz = (bid & 7) * 128 + (bid >> 3);   // XCD-aware (1024 % 8 == 0)
    const int bm = swz >> 4;      // 0..63
    const int bn = swz & 15;      // 0..15
    const int tid = threadIdx.x;
    const int wave = tid >> 6, lane = tid & 63;
    const int wr = wave >> 1, wc = wave & 1;
    const int srow = lane >> 2, scol = (lane & 3) * 8;
    const int rsel = lane & 15;
    const int kq = (lane >> 4) * 8;
    const int c0 = wave * 2, c1 = wave * 2 + 1;

    f32x4 acc[4][4];
#pragma unroll
    for (int m = 0; m < 4; ++m)
#pragma unroll
        for (int n = 0; n < 4; ++n) acc[m][n] = f32x4{0.f, 0.f, 0.f, 0.f};

    const u16* gA = g_ah + (size_t)(bm * 128) * DD;
    const u16* gB = g_bh + (size_t)(bn * 128) * DD;
    const size_t off0 = (size_t)(c0 * 16 + srow) * DD + scol;
    const size_t off1 = (size_t)(c1 * 16 + srow) * DD + scol;

    // prologue: stage tile 0 into buffer 0
    gload16(gA + off0, &As[0][c0 * 512]);
    gload16(gA + off1, &As[0][c1 * 512]);
    gload16(gB + off0, &Bs[0][c0 * 512]);
    gload16(gB + off1, &Bs[0][c1 * 512]);
    __syncthreads();

    int cur = 0;
    for (int step = 0; step < 64; ++step) {
        if (step < 63) {   // issue next-tile loads FIRST; they complete under compute
            size_t k1 = (size_t)(step + 1) * 32;
            gload16(gA + off0 + k1, &As[cur ^ 1][c0 * 512]);
            gload16(gA + off1 + k1, &As[cur ^ 1][c1 * 512]);
            gload16(gB + off0 + k1, &Bs[cur ^ 1][c0 * 512]);
            gload16(gB + off1 + k1, &Bs[cur ^ 1][c1 * 512]);
        }
        bfrag a[4], b[4];
#pragma unroll
        for (int m = 0; m < 4; ++m) a[m] = *(const bfrag*)&As[cur][(wr * 64 + m * 16 + rsel) * 32 + kq];
#pragma unroll
        for (int n = 0; n < 4; ++n) b[n] = *(const bfrag*)&Bs[cur][(wc * 64 + n * 16 + rsel) * 32 + kq];
#pragma unroll
        for (int m = 0; m < 4; ++m)
#pragma unroll
            for (int n = 0; n < 4; ++n)
                acc[m][n] = __builtin_amdgcn_mfma_f32_16x16x32_bf16(a[m], b[n], acc[m][n], 0, 0, 0);
        __syncthreads();   // drains prefetch (mostly landed) + guards buffer swap
        cur ^= 1;
    }

    // epilogue: tanh + weighted reduce over this wave's 64 n-columns -> atomic scores
    const int cl = lane & 15, gq = lane >> 4;
    float ccv[4], wv[4];
#pragma unroll
    for (int nf = 0; nf < 4; ++nf) {
        int n = bn * 128 + wc * 64 + nf * 16 + cl;
        ccv[nf] = g_cc[n];
        wv[nf] = Wsc[n];
    }
#pragma unroll
    for (int m = 0; m < 4; ++m) {
#pragma unroll
        for (int r = 0; r < 4; ++r) {
            float v = 0.0f;
#pragma unroll
            for (int nf = 0; nf < 4; ++nf) v += ftanh(acc[m][nf][r] + ccv[nf]) * wv[nf];
            v += __shfl_xor(v, 1); v += __shfl_xor(v, 2);
            v += __shfl_xor(v, 4); v += __shfl_xor(v, 8);
            if (cl == 0) atomicAdd(&g_scores[bm * 128 + wr * 64 + m * 16 + gq * 4 + r], v);
        }
    }
}

// ---------------- softmax over 8192 scores ----------------
__global__ __launch_bounds__(1024) void softmax_k(float* __restrict__ out_alpha) {
    __shared__ float red[16];
    __shared__ float sval;
    int t = threadIdx.x, lane = t & 63, w = t >> 6;
    float loc[8];
    float m = -1e30f;
#pragma unroll
    for (int i = 0; i < 8; ++i) {
        loc[i] = g_scores[t + i * 1024];
        m = fmaxf(m, loc[i]);
    }
#pragma unroll
    for (int o = 1; o < 64; o <<= 1) m = fmaxf(m, __shfl_xor(m, o));
    if (lane == 0) red[w] = m;
    __syncthreads();
    if (t == 0) { float mm = red[0]; for (int i = 1; i < 16; ++i) mm = fmaxf(mm, red[i]); sval = mm; }
    __syncthreads();
    float mx = sval, s = 0.0f;
#pragma unroll
    for (int i = 0; i < 8; ++i) { loc[i] = __expf(loc[i] - mx); s += loc[i]; }
#pragma unroll
    for (int o = 1; o < 64; o <<= 1) s += __shfl_xor(s, o);
    if (lane == 0) red[w] = s;
    __syncthreads();
    if (t == 0) { float ss = 0; for (int i = 0; i < 16; ++i) ss += red[i]; sval = ss; }
    __syncthreads();
    float inv = 1.0f / sval;
#pragma unroll
    for (int i = 0; i < 8; ++i) {
        float a = loc[i] * inv;
        g_alpha[t + i * 1024] = a;
        out_alpha[t + i * 1024] = a;
    }
}

// ---------------- ctx += alpha @ enc  (bf16 enc from g_ah) ----------------
__global__ __launch_bounds__(256) void ctx_partial_k() {
    int t = threadIdx.x, b = blockIdx.x;   // 128 blocks x 64 s-rows
    int d0 = t * 8;
    float acc[8] = {0, 0, 0, 0, 0, 0, 0, 0};
    int s0 = b * 64;
    for (int s = s0; s < s0 + 64; ++s) {
        u16x8 v = *(const u16x8*)&g_ah[(size_t)s * DD + d0];
        float a = g_alpha[s];
#pragma unroll
        for (int e = 0; e < 8; ++e) acc[e] += a * bf2f(v[e]);
    }
#pragma unroll
    for (int e = 0; e < 8; ++e) atomicAdd(&g_ctx[d0 + e], acc[e]);
}

// ---------------- heads ----------------
__global__ __launch_bounds__(256) void heads_k(const float* __restrict__ Wsym, const float* __restrict__ bsym,
                                               const float* __restrict__ Wrel, const float* __restrict__ brel,
                                               float* __restrict__ out) {
    int wv = threadIdx.x >> 6, lane = threadIdx.x & 63;
    int row = blockIdx.x * 4 + wv;
    if (row >= VV + RR) return;
    const float* wp;
    float bb;
    if (row < VV) { wp = Wsym + (size_t)row * DD; bb = bsym[row]; }
    else          { wp = Wrel + (size_t)(row - VV) * DD; bb = brel[row - VV]; }
    float acc = 0.0f;
#pragma unroll
    for (int j = 0; j < 4; ++j) {
        int base = j * 512 + lane * 8;
        f32x4 w0 = *(const f32x4*)&wp[base];
        f32x4 w1 = *(const f32x4*)&wp[base + 4];
        f32x4 x0 = *(const f32x4*)&g_cb[base];
        f32x4 x1 = *(const f32x4*)&g_cb[base + 4];
#pragma unroll
        for (int e = 0; e < 4; ++e) acc += w0[e] * x0[e] + w1[e] * x1[e];
    }
#pragma unroll
    for (int o = 1; o < 64; o <<= 1) acc += __shfl_xor(acc, o);
    if (lane == 0) out[row] = acc + bb;
}

extern "C" void kernel_launch(void* const* d_in, const int* in_sizes, int n_in,
                              void* d_out, int out_size, void* d_ws, size_t ws_size,
                              hipStream_t stream) {
    float* out = (float*)d_out;   // f32 outputs

    static const int expected[24] = {
        SS * DD, DD, DD, DD,
        3 * DD * DD, 3 * DD * DD, 3 * DD, 3 * DD,
        3 * DD * DD, 3 * DD * DD, 3 * DD, 3 * DD,
        DD * DD, DD, DD * DD, DD, DD * DD, DD,
        DD, 1, VV * DD, VV, RR * DD, RR
    };
    if (n_in != 24) { diag_k<<<1, 1, 0, stream>>>(out, 4.0e7f); return; }
    for (int i = 0; i < 24; ++i)
        if (in_sizes[i] != expected[i]) { diag_k<<<1, 1, 0, stream>>>(out, 3.0e7f + (i + 1) * 1.0e5f); return; }

    const float* enc     = (const float*)d_in[0];
    const float* cprev   = (const float*)d_in[1];
    const float* partner = (const float*)d_in[2];
    const float* cov     = (const float*)d_in[3];
    const float* Wih_a   = (const float*)d_in[4];
    const float* Whh_a   = (const float*)d_in[5];
    const float* bih_a   = (const float*)d_in[6];
    const float* bhh_a   = (const float*)d_in[7];
    const float* Wih_b   = (const float*)d_in[8];
    const float* Whh_b   = (const float*)d_in[9];
    const float* bih_b   = (const float*)d_in[10];
    const float* bhh_b   = (const float*)d_in[11];
    const float* W_enc   = (const float*)d_in[12];
    const float* b_enc   = (const float*)d_in[13];
    const float* W_co    = (const float*)d_in[14];
    const float* b_co    = (const float*)d_in[15];
    const float* W_cov   = (const float*)d_in[16];
    const float* b_cov   = (const float*)d_in[17];
    const float* W_score = (const float*)d_in[18];
    const float* W_sym   = (const float*)d_in[20];
    const float* b_sym   = (const float*)d_in[21];
    const float* W_rel   = (const float*)d_in[22];
    const float* b_rel   = (const float*)d_in[23];

    presplit_k<0><<<SS * DD / (256 * 8), 256, 0, stream>>>(enc);
    presplit_k<1><<<DD * DD / (256 * 8), 256, 0, stream>>>(W_enc);   // also zeroes scores+ctx
    matvec2_k<0><<<2 * (GATE / 4), 256, 0, stream>>>(Wih_a, Whh_a, partner, cprev, bih_a, bhh_a);
    gru_out_k<0><<<8, 256, 0, stream>>>(cprev, nullptr);
    cc_k<<<DD / 4, 256, 0, stream>>>(W_co, W_cov, cov, b_enc, b_co, b_cov);
    score_gemm_k<<<1024, 256, 0, stream>>>(W_score);
    softmax_k<<<1, 1024, 0, stream>>>(out + VV + RR + DD);
    ctx_partial_k<<<128, 256, 0, stream>>>();
    matvec2_k<1><<<2 * (GATE / 4), 256, 0, stream>>>(Wih_b, Whh_b, nullptr, nullptr, bih_b, bhh_b);
    gru_out_k<1><<<8, 256, 0, stream>>>(cprev, out + VV + RR);
    heads_k<<<(VV + RR + 3) / 4, 256, 0, stream>>>(W_sym, b_sym, W_rel, b_rel, out);
}